// Round 2
// baseline (2019.250 us; speedup 1.0000x reference)
//
#include <hip/hip_runtime.h>
#include <cstdint>
#include <cstddef>

#define B_  2
#define S_  2048
#define H_  768
#define NH  12
#define DH  64
#define RD  5
#define BN  (B_*NH)   // 24

typedef unsigned short u16;

__device__ __forceinline__ float b2f(u16 u) {
    return __uint_as_float(((unsigned int)u) << 16);
}
__device__ __forceinline__ u16 f2b(float f) {
    unsigned int x = __float_as_uint(f);
    unsigned int r = x + 0x7FFFu + ((x >> 16) & 1u);   // RNE
    return (u16)(r >> 16);
}

// ---------------------------------------------------------------------------
// Kernel 1: fused QKV projection.  y = x @ W.T + b -> [b][n][s][d] (bf16 ws).
// Inputs fp32.  Tile 64(M) x 64(N), K-step 32, 256 threads, 4x4 per thread.
// grid.x in [0,36): 12 col-tiles each for q, k, v.  grid.y in [0,64): row tiles.
// ---------------------------------------------------------------------------
__global__ __launch_bounds__(256) void qkv_gemm(
    const float* __restrict__ x,
    const float* __restrict__ Wq, const float* __restrict__ bq,
    const float* __restrict__ Wk, const float* __restrict__ bk,
    const float* __restrict__ Wv, const float* __restrict__ bv,
    u16* __restrict__ qo, u16* __restrict__ ko, u16* __restrict__ vo)
{
    __shared__ float Xs[32][68];
    __shared__ float Ws[32][68];

    const int tid = threadIdx.x;
    const int jg0 = blockIdx.x * 64;
    const int which = jg0 / H_;          // 0=q 1=k 2=v
    const int j0 = jg0 % H_;
    const int m0 = blockIdx.y * 64;

    const float* W    = (which == 0) ? Wq : (which == 1) ? Wk : Wv;
    const float* bias = (which == 0) ? bq : (which == 1) ? bk : bv;
    u16*         out  = (which == 0) ? qo : (which == 1) ? ko : vo;

    const int tx = tid & 15, ty = tid >> 4;
    float c[4][4] = {};

    for (int k0 = 0; k0 < H_; k0 += 32) {
        // stage X tile: 64 rows x 32 k (8 floats = two float4 per thread)
        {
            int e = tid * 8;
            int row = e >> 5, kk = e & 31;
            const float* src = x + (size_t)(m0 + row) * H_ + k0 + kk;
            float4 r0 = *(const float4*)(src);
            float4 r1 = *(const float4*)(src + 4);
            Xs[kk + 0][row] = r0.x; Xs[kk + 1][row] = r0.y;
            Xs[kk + 2][row] = r0.z; Xs[kk + 3][row] = r0.w;
            Xs[kk + 4][row] = r1.x; Xs[kk + 5][row] = r1.y;
            Xs[kk + 6][row] = r1.z; Xs[kk + 7][row] = r1.w;
        }
        // stage W tile: 64 cols x 32 k
        {
            int e = tid * 8;
            int jl = e >> 5, kk = e & 31;
            const float* src = W + (size_t)(j0 + jl) * H_ + k0 + kk;
            float4 r0 = *(const float4*)(src);
            float4 r1 = *(const float4*)(src + 4);
            Ws[kk + 0][jl] = r0.x; Ws[kk + 1][jl] = r0.y;
            Ws[kk + 2][jl] = r0.z; Ws[kk + 3][jl] = r0.w;
            Ws[kk + 4][jl] = r1.x; Ws[kk + 5][jl] = r1.y;
            Ws[kk + 6][jl] = r1.z; Ws[kk + 7][jl] = r1.w;
        }
        __syncthreads();

#pragma unroll
        for (int kk = 0; kk < 32; ++kk) {
            float4 a4 = *(const float4*)&Xs[kk][4 * ty];
            float4 b4 = *(const float4*)&Ws[kk][4 * tx];
            float a[4] = {a4.x, a4.y, a4.z, a4.w};
            float bb[4] = {b4.x, b4.y, b4.z, b4.w};
#pragma unroll
            for (int ii = 0; ii < 4; ++ii)
#pragma unroll
                for (int jj = 0; jj < 4; ++jj)
                    c[ii][jj] += a[ii] * bb[jj];
        }
        __syncthreads();
    }

    const int n = j0 >> 6;               // head index (tile never straddles heads)
    float bvv[4];
#pragma unroll
    for (int jj = 0; jj < 4; ++jj) bvv[jj] = bias[j0 + 4 * tx + jj];

#pragma unroll
    for (int ii = 0; ii < 4; ++ii) {
        int m = m0 + 4 * ty + ii;
        int b = m >> 11, s = m & 2047;
        size_t base = ((size_t)(b * NH + n) * S_ + s) * DH + 4 * tx;
        ushort4 pk;
        pk.x = f2b(c[ii][0] + bvv[0]);
        pk.y = f2b(c[ii][1] + bvv[1]);
        pk.z = f2b(c[ii][2] + bvv[2]);
        pk.w = f2b(c[ii][3] + bvv[3]);
        *(ushort4*)(out + base) = pk;
    }
}

// ---------------------------------------------------------------------------
// Kernel 2: flash-style attention with biaffine structural bias.
// Block = (bn, 16-row i-tile), 256 threads.  q' built in LDS per block.
// q/k/v are bf16 ws; bili/adj/mask/absb fp32; out fp32.
// ---------------------------------------------------------------------------
__global__ __launch_bounds__(256) void attn(
    const u16* __restrict__ q, const u16* __restrict__ k, const u16* __restrict__ v,
    const float* __restrict__ bili, const float* __restrict__ adj,
    const float* __restrict__ mask, const float* __restrict__ absb,
    float* __restrict__ out)
{
    __shared__ float Qs[16][68];
    __shared__ float QPs[RD][16][68];
    __shared__ float Kt[64][68];      // Kt[d][j]; also scratch for bili M
    __shared__ float Vs[64][64];      // Vs[j][d]
    __shared__ float Pt[64][20];      // probs^T [j][i]
    __shared__ float mrow[16], lrow[16], arow[16];

    const int tid = threadIdx.x;
    const int bn = blockIdx.x;        // 0..23  (fastest -> heads share adj in L2/L3)
    const int it = blockIdx.y;        // 0..127
    const int b = bn / NH, n = bn % NH;
    const int i0 = it * 16;

    const size_t kbase = (size_t)bn * S_ * DH;

    // stage Q rows
    for (int e = tid; e < 16 * 64; e += 256) {
        int i = e >> 6, d = e & 63;
        Qs[i][d] = b2f(q[kbase + (size_t)(i0 + i) * DH + d]);
    }
    if (tid < 16) { mrow[tid] = -1e30f; lrow[tid] = 0.f; arow[tid] = 0.f; }
    __syncthreads();

    // build QPs[r] = Qs @ M_r   (M_r staged into Kt scratch)
    for (int r = 0; r < RD; ++r) {
        for (int e = tid; e < 64 * 64; e += 256) {
            int p = e >> 6, d = e & 63;
            Kt[p][d] = bili[((size_t)(r * NH + n) * DH + p) * DH + d];
        }
        __syncthreads();
        {
            int d = tid & 63, iw = tid >> 6;
#pragma unroll
            for (int xx = 0; xx < 4; ++xx) {
                int i = 4 * iw + xx;
                float t = 0.f;
#pragma unroll 8
                for (int p = 0; p < 64; ++p) t += Qs[i][p] * Kt[p][d];
                QPs[r][i][d] = t;
            }
        }
        __syncthreads();
    }

    float ab[RD];
#pragma unroll
    for (int r = 0; r < RD; ++r) ab[r] = absb[r * NH + n];

    float acc[4] = {0.f, 0.f, 0.f, 0.f};
    const int si = tid >> 4;          // scores row 0..15
    const int jq = tid & 15;          // j-quad
    const int pd = tid & 63;          // PV: d
    const int pw = tid >> 6;          // PV: rows 4*pw..4*pw+3

    for (int t = 0; t < 32; ++t) {
        const int j0 = t * 64;
        // stage K (transposed) and V
        for (int e = tid; e < 64 * 64; e += 256) {
            int j = e >> 6, d = e & 63;
            Kt[d][j] = b2f(k[kbase + (size_t)(j0 + j) * DH + d]);
            Vs[j][d] = b2f(v[kbase + (size_t)(j0 + j) * DH + d]);
        }
        __syncthreads();

        // ---- scores: 6 relations x 4 j's per thread ----
        float s[6][4] = {};
        for (int dc = 0; dc < 64; dc += 4) {
            float qv[6][4];
            {
                float4 t0 = *(const float4*)&Qs[si][dc];
                qv[0][0] = t0.x; qv[0][1] = t0.y; qv[0][2] = t0.z; qv[0][3] = t0.w;
            }
#pragma unroll
            for (int r = 0; r < RD; ++r) {
                float4 tr = *(const float4*)&QPs[r][si][dc];
                qv[1 + r][0] = tr.x; qv[1 + r][1] = tr.y;
                qv[1 + r][2] = tr.z; qv[1 + r][3] = tr.w;
            }
#pragma unroll
            for (int u = 0; u < 4; ++u) {
                float4 kq = *(const float4*)&Kt[dc + u][4 * jq];
#pragma unroll
                for (int rel = 0; rel < 6; ++rel) {
                    float qf = qv[rel][u];
                    s[rel][0] += qf * kq.x;
                    s[rel][1] += qf * kq.y;
                    s[rel][2] += qf * kq.z;
                    s[rel][3] += qf * kq.w;
                }
            }
        }

        // ---- combine with adjacency, abs bias, scale, mask ----
        const int ig = i0 + si;
        float av[RD][4];
#pragma unroll
        for (int r = 0; r < RD; ++r) {
            float4 a4 = *(const float4*)(adj + ((size_t)(r * B_ + b) * S_ + ig) * S_ + j0 + 4 * jq);
            av[r][0] = a4.x; av[r][1] = a4.y; av[r][2] = a4.z; av[r][3] = a4.w;
        }
        float4 mk4 = *(const float4*)(mask + (size_t)b * S_ + j0 + 4 * jq);
        float mkf[4] = {mk4.x, mk4.y, mk4.z, mk4.w};

        float sc[4];
#pragma unroll
        for (int c2 = 0; c2 < 4; ++c2) {
            float tt = s[0][c2];
#pragma unroll
            for (int r = 0; r < RD; ++r) tt += av[r][c2] * (s[1 + r][c2] + ab[r]);
            sc[c2] = tt * 0.125f + mkf[c2];
        }

        // ---- online softmax (rows of 16 lanes) ----
        float mx = fmaxf(fmaxf(sc[0], sc[1]), fmaxf(sc[2], sc[3]));
#pragma unroll
        for (int o = 1; o < 16; o <<= 1) mx = fmaxf(mx, __shfl_xor(mx, o));
        float mold = mrow[si];
        float mnew = fmaxf(mold, mx);
        float p4[4];
        float ls = 0.f;
#pragma unroll
        for (int c2 = 0; c2 < 4; ++c2) { p4[c2] = __expf(sc[c2] - mnew); ls += p4[c2]; }
#pragma unroll
        for (int o = 1; o < 16; o <<= 1) ls += __shfl_xor(ls, o);
        if (jq == 0) {
            float alpha = __expf(mold - mnew);
            arow[si] = alpha;
            lrow[si] = lrow[si] * alpha + ls;
            mrow[si] = mnew;
        }
#pragma unroll
        for (int c2 = 0; c2 < 4; ++c2) Pt[4 * jq + c2][si] = p4[c2];
        __syncthreads();

        // ---- PV accumulate ----
        float al[4];
#pragma unroll
        for (int rr = 0; rr < 4; ++rr) al[rr] = arow[4 * pw + rr];
#pragma unroll
        for (int rr = 0; rr < 4; ++rr) acc[rr] *= al[rr];
#pragma unroll 8
        for (int j = 0; j < 64; ++j) {
            float vv = Vs[j][pd];
            float4 pp = *(const float4*)&Pt[j][4 * pw];
            acc[0] += pp.x * vv;
            acc[1] += pp.y * vv;
            acc[2] += pp.z * vv;
            acc[3] += pp.w * vv;
        }
        __syncthreads();
    }

    // epilogue: normalize and write [b][s][n*64+d] fp32
#pragma unroll
    for (int rr = 0; rr < 4; ++rr) {
        int row = 4 * pw + rr;
        float o = acc[rr] / lrow[row];
        out[((size_t)b * S_ + i0 + row) * H_ + n * DH + pd] = o;
    }
}

// ---------------------------------------------------------------------------
extern "C" void kernel_launch(void* const* d_in, const int* in_sizes, int n_in,
                              void* d_out, int out_size, void* d_ws, size_t ws_size,
                              hipStream_t stream)
{
    const float* hs   = (const float*)d_in[0];
    const float* mask = (const float*)d_in[1];
    const float* adj  = (const float*)d_in[2];
    const float* Wq   = (const float*)d_in[3];
    const float* bq   = (const float*)d_in[4];
    const float* Wk   = (const float*)d_in[5];
    const float* bk   = (const float*)d_in[6];
    const float* Wv   = (const float*)d_in[7];
    const float* bv   = (const float*)d_in[8];
    const float* bili = (const float*)d_in[9];
    const float* absb = (const float*)d_in[10];
    float* out = (float*)d_out;

    u16* q = (u16*)d_ws;
    u16* k = q + (size_t)BN * S_ * DH;
    u16* v = k + (size_t)BN * S_ * DH;

    qkv_gemm<<<dim3(36, 64), 256, 0, stream>>>(hs, Wq, bq, Wk, bk, Wv, bv, q, k, v);
    attn<<<dim3(BN, 128), 256, 0, stream>>>(q, k, v, bili, adj, mask, absb, out);
}

// Round 3
// 680.215 us; speedup vs baseline: 2.9685x; 2.9685x over previous
//
#include <hip/hip_runtime.h>
#include <cstdint>
#include <cstddef>

#define B_  2
#define S_  2048
#define H_  768
#define NH  12
#define DH  64
#define RD  5
#define BN  (B_*NH)   // 24

typedef unsigned short u16;
typedef __attribute__((ext_vector_type(8))) short bf16x8;
typedef __attribute__((ext_vector_type(4))) float f32x4;

__device__ __forceinline__ float b2f(u16 u) {
    return __uint_as_float(((unsigned int)u) << 16);
}
__device__ __forceinline__ u16 f2b(float f) {
    unsigned int x = __float_as_uint(f);
    unsigned int r = x + 0x7FFFu + ((x >> 16) & 1u);   // RNE
    return (u16)(r >> 16);
}

// ---------------------------------------------------------------------------
// Kernel 1: fused QKV projection.  y = x @ W.T + b -> bf16 [b][n][s][d].
// ---------------------------------------------------------------------------
__global__ __launch_bounds__(256) void qkv_gemm(
    const float* __restrict__ x,
    const float* __restrict__ Wq, const float* __restrict__ bq,
    const float* __restrict__ Wk, const float* __restrict__ bk,
    const float* __restrict__ Wv, const float* __restrict__ bv,
    u16* __restrict__ qo, u16* __restrict__ ko, u16* __restrict__ vo)
{
    __shared__ float Xs[32][68];
    __shared__ float Ws[32][68];

    const int tid = threadIdx.x;
    const int jg0 = blockIdx.x * 64;
    const int which = jg0 / H_;          // 0=q 1=k 2=v
    const int j0 = jg0 % H_;
    const int m0 = blockIdx.y * 64;

    const float* W    = (which == 0) ? Wq : (which == 1) ? Wk : Wv;
    const float* bias = (which == 0) ? bq : (which == 1) ? bk : bv;
    u16*         out  = (which == 0) ? qo : (which == 1) ? ko : vo;

    const int tx = tid & 15, ty = tid >> 4;
    float c[4][4] = {};

    for (int k0 = 0; k0 < H_; k0 += 32) {
        {
            int e = tid * 8;
            int row = e >> 5, kk = e & 31;
            const float* src = x + (size_t)(m0 + row) * H_ + k0 + kk;
            float4 r0 = *(const float4*)(src);
            float4 r1 = *(const float4*)(src + 4);
            Xs[kk + 0][row] = r0.x; Xs[kk + 1][row] = r0.y;
            Xs[kk + 2][row] = r0.z; Xs[kk + 3][row] = r0.w;
            Xs[kk + 4][row] = r1.x; Xs[kk + 5][row] = r1.y;
            Xs[kk + 6][row] = r1.z; Xs[kk + 7][row] = r1.w;
        }
        {
            int e = tid * 8;
            int jl = e >> 5, kk = e & 31;
            const float* src = W + (size_t)(j0 + jl) * H_ + k0 + kk;
            float4 r0 = *(const float4*)(src);
            float4 r1 = *(const float4*)(src + 4);
            Ws[kk + 0][jl] = r0.x; Ws[kk + 1][jl] = r0.y;
            Ws[kk + 2][jl] = r0.z; Ws[kk + 3][jl] = r0.w;
            Ws[kk + 4][jl] = r1.x; Ws[kk + 5][jl] = r1.y;
            Ws[kk + 6][jl] = r1.z; Ws[kk + 7][jl] = r1.w;
        }
        __syncthreads();

#pragma unroll
        for (int kk = 0; kk < 32; ++kk) {
            float4 a4 = *(const float4*)&Xs[kk][4 * ty];
            float4 b4 = *(const float4*)&Ws[kk][4 * tx];
            float a[4] = {a4.x, a4.y, a4.z, a4.w};
            float bb[4] = {b4.x, b4.y, b4.z, b4.w};
#pragma unroll
            for (int ii = 0; ii < 4; ++ii)
#pragma unroll
                for (int jj = 0; jj < 4; ++jj)
                    c[ii][jj] += a[ii] * bb[jj];
        }
        __syncthreads();
    }

    const int n = j0 >> 6;
    float bvv[4];
#pragma unroll
    for (int jj = 0; jj < 4; ++jj) bvv[jj] = bias[j0 + 4 * tx + jj];

#pragma unroll
    for (int ii = 0; ii < 4; ++ii) {
        int m = m0 + 4 * ty + ii;
        int b = m >> 11, s = m & 2047;
        size_t base = ((size_t)(b * NH + n) * S_ + s) * DH + 4 * tx;
        ushort4 pk;
        pk.x = f2b(c[ii][0] + bvv[0]);
        pk.y = f2b(c[ii][1] + bvv[1]);
        pk.z = f2b(c[ii][2] + bvv[2]);
        pk.w = f2b(c[ii][3] + bvv[3]);
        *(ushort4*)(out + base) = pk;
    }
}

// ---------------------------------------------------------------------------
// Kernel 2: transpose V -> vt[bn][d][s]  (B-fragment friendly for PV MFMA)
// ---------------------------------------------------------------------------
__global__ __launch_bounds__(256) void vtrans(
    const u16* __restrict__ v, u16* __restrict__ vt)
{
    __shared__ u16 T[64][72];
    const int tid = threadIdx.x;
    const int bn = blockIdx.x;
    const int s0 = blockIdx.y * 64;
    const size_t base = (size_t)bn * S_ * DH;

    {
        int r = tid >> 2, d0 = (tid & 3) * 16;
        const u16* src = v + base + (size_t)(s0 + r) * DH + d0;
        *(bf16x8*)&T[r][d0]     = *(const bf16x8*)(src);
        *(bf16x8*)&T[r][d0 + 8] = *(const bf16x8*)(src + 8);
    }
    __syncthreads();
    {
        int d = tid >> 2, c0 = (tid & 3) * 16;
        u16 tmp[16];
#pragma unroll
        for (int u = 0; u < 16; ++u) tmp[u] = T[c0 + u][d];
        u16* dst = vt + (size_t)bn * DH * S_ + (size_t)d * S_ + s0 + c0;
        *(bf16x8*)(dst)     = *(const bf16x8*)&tmp[0];
        *(bf16x8*)(dst + 8) = *(const bf16x8*)&tmp[8];
    }
}

// ---------------------------------------------------------------------------
// Kernel 3: pack binary adjacency -> bytes, i-quad interleaved:
// adjp[((b*512 + (i>>2))*2048 + j)*4 + (i&3)] = sum_r bit_r
// ---------------------------------------------------------------------------
__global__ __launch_bounds__(256) void adjpack(
    const float* __restrict__ adj, unsigned char* __restrict__ adjp)
{
    const int idx = blockIdx.x * 256 + threadIdx.x;   // [0, 2^21)
    const int j  = idx & 2047;
    const int iq = (idx >> 11) & 511;
    const int b  = idx >> 20;
    unsigned int bits[4] = {0, 0, 0, 0};
#pragma unroll
    for (int r = 0; r < RD; ++r) {
#pragma unroll
        for (int ii = 0; ii < 4; ++ii) {
            float a = adj[(((size_t)(r * B_ + b) * S_) + iq * 4 + ii) * S_ + j];
            bits[ii] |= (a != 0.f ? 1u : 0u) << r;
        }
    }
    uchar4 pk;
    pk.x = (unsigned char)bits[0];
    pk.y = (unsigned char)bits[1];
    pk.z = (unsigned char)bits[2];
    pk.w = (unsigned char)bits[3];
    *(uchar4*)(adjp + (size_t)idx * 4) = pk;
}

// ---------------------------------------------------------------------------
// Kernel 4: MFMA flash attention with biaffine structural bias.
// Block = (bn, 64-row i-tile), 256 thr = 4 independent waves (16 rows each).
// No __syncthreads in the j-loop.
// ---------------------------------------------------------------------------
__global__ __launch_bounds__(256, 3) void attn(
    const u16* __restrict__ q, const u16* __restrict__ k, const u16* __restrict__ vt,
    const float* __restrict__ bili, const unsigned char* __restrict__ adjp,
    const float* __restrict__ mask, const float* __restrict__ absb,
    float* __restrict__ out)
{
    __shared__ u16 Mt[64][72];        // M_r transposed: Mt[q][p]
    __shared__ u16 Pbuf[4][16][72];   // per-wave P / Q' round-trip

    const int tid = threadIdx.x;
    const int bn = blockIdx.x;        // 0..23
    const int it = blockIdx.y;        // 0..31
    const int b = bn / NH, n = bn % NH;
    const int w = tid >> 6;           // wave id
    const int lane = tid & 63;
    const int l15 = lane & 15;
    const int quad = lane >> 4;
    const int wi0 = it * 64 + w * 16; // this wave's 16 rows

    const size_t kbase = (size_t)bn * S_ * DH;

    // ---- A-frags for Q (loop-invariant) ----
    const u16* qrow = q + kbase + (size_t)(wi0 + l15) * DH + quad * 8;
    bf16x8 aq0 = *(const bf16x8*)(qrow);
    bf16x8 aq1 = *(const bf16x8*)(qrow + 32);

    // ---- build Q'_r A-frags via MFMA (M_r staged transposed in LDS) ----
    bf16x8 aqp[RD][2];
#pragma unroll 1
    for (int r = 0; r < RD; ++r) {
        __syncthreads();              // previous iter's Mt readers done
        {
            int p = tid >> 2, q0 = (tid & 3) * 16;
            const float* src = bili + ((size_t)(r * NH + n) * DH + p) * DH + q0;
            float4 m0 = *(const float4*)(src);
            float4 m1 = *(const float4*)(src + 4);
            float4 m2 = *(const float4*)(src + 8);
            float4 m3 = *(const float4*)(src + 12);
            float mv[16] = {m0.x, m0.y, m0.z, m0.w, m1.x, m1.y, m1.z, m1.w,
                            m2.x, m2.y, m2.z, m2.w, m3.x, m3.y, m3.z, m3.w};
#pragma unroll
            for (int u = 0; u < 16; ++u) Mt[q0 + u][p] = f2b(mv[u]);
        }
        __syncthreads();
#pragma unroll
        for (int ns = 0; ns < 4; ++ns) {
            bf16x8 b0 = *(const bf16x8*)&Mt[ns * 16 + l15][quad * 8];
            bf16x8 b1 = *(const bf16x8*)&Mt[ns * 16 + l15][quad * 8 + 32];
            f32x4 d = {0.f, 0.f, 0.f, 0.f};
            d = __builtin_amdgcn_mfma_f32_16x16x32_bf16(aq0, b0, d, 0, 0, 0);
            d = __builtin_amdgcn_mfma_f32_16x16x32_bf16(aq1, b1, d, 0, 0, 0);
#pragma unroll
            for (int reg = 0; reg < 4; ++reg)
                Pbuf[w][quad * 4 + reg][ns * 16 + l15] = f2b(d[reg]);
        }
        aqp[r][0] = *(const bf16x8*)&Pbuf[w][l15][quad * 8];
        aqp[r][1] = *(const bf16x8*)&Pbuf[w][l15][quad * 8 + 32];
    }

    float ab[RD];
#pragma unroll
    for (int r = 0; r < RD; ++r) ab[r] = absb[r * NH + n];

    bf16x8 ones;
#pragma unroll
    for (int u = 0; u < 8; ++u) ones[u] = (short)0x3F80;   // bf16 1.0

    f32x4 o[4] = {{0,0,0,0},{0,0,0,0},{0,0,0,0},{0,0,0,0}};
    f32x4 lacc = {0.f, 0.f, 0.f, 0.f};
    float m_r[4] = {-1e30f, -1e30f, -1e30f, -1e30f};

    const unsigned char* adjrow = adjp +
        ((size_t)(b * 512 + (wi0 >> 2) + quad) * S_) * 4;
    const float* maskrow = mask + (size_t)b * S_;
    const size_t vtb = (size_t)bn * DH * S_;

    for (int t = 0; t < 32; ++t) {
        const int j0 = t * 64;
        float sc[4][4];

#pragma unroll
        for (int js = 0; js < 4; ++js) {
            const int jcol = j0 + js * 16 + l15;
            const u16* kp = k + kbase + (size_t)jcol * DH + quad * 8;
            bf16x8 bk0 = *(const bf16x8*)(kp);
            bf16x8 bk1 = *(const bf16x8*)(kp + 32);

            f32x4 a_qk = {0.f, 0.f, 0.f, 0.f};
            a_qk = __builtin_amdgcn_mfma_f32_16x16x32_bf16(aq0, bk0, a_qk, 0, 0, 0);
            a_qk = __builtin_amdgcn_mfma_f32_16x16x32_bf16(aq1, bk1, a_qk, 0, 0, 0);
            f32x4 a_r[RD];
#pragma unroll
            for (int r = 0; r < RD; ++r) {
                f32x4 z = {0.f, 0.f, 0.f, 0.f};
                z = __builtin_amdgcn_mfma_f32_16x16x32_bf16(aqp[r][0], bk0, z, 0, 0, 0);
                z = __builtin_amdgcn_mfma_f32_16x16x32_bf16(aqp[r][1], bk1, z, 0, 0, 0);
                a_r[r] = z;
            }

            uchar4 a4 = *(const uchar4*)(adjrow + (size_t)jcol * 4);
            unsigned int ab4[4] = {a4.x, a4.y, a4.z, a4.w};
            float mk = maskrow[jcol];
#pragma unroll
            for (int reg = 0; reg < 4; ++reg) {
                float s = a_qk[reg];
#pragma unroll
                for (int r = 0; r < RD; ++r) {
                    float bit = (float)((ab4[reg] >> r) & 1u);
                    s += bit * (a_r[r][reg] + ab[r]);
                }
                sc[js][reg] = s * 0.125f + mk;
            }
        }

        // ---- online softmax (rows live in 16-lane quad groups) ----
        float alpha[4], mnew[4];
#pragma unroll
        for (int reg = 0; reg < 4; ++reg) {
            float nm = fmaxf(fmaxf(sc[0][reg], sc[1][reg]),
                             fmaxf(sc[2][reg], sc[3][reg]));
#pragma unroll
            for (int o2 = 1; o2 < 16; o2 <<= 1)
                nm = fmaxf(nm, __shfl_xor(nm, o2));
            mnew[reg] = fmaxf(m_r[reg], nm);
            alpha[reg] = __expf(m_r[reg] - mnew[reg]);
            m_r[reg] = mnew[reg];
        }
#pragma unroll
        for (int js = 0; js < 4; ++js)
#pragma unroll
            for (int reg = 0; reg < 4; ++reg) {
                float p = __expf(sc[js][reg] - mnew[reg]);
                Pbuf[w][quad * 4 + reg][js * 16 + l15] = f2b(p);
            }
#pragma unroll
        for (int reg = 0; reg < 4; ++reg) {
            lacc[reg] *= alpha[reg];
#pragma unroll
            for (int ds = 0; ds < 4; ++ds) o[ds][reg] *= alpha[reg];
        }

        // ---- PV + row-sum via MFMA ----
        bf16x8 pa0 = *(const bf16x8*)&Pbuf[w][l15][quad * 8];
        bf16x8 pa1 = *(const bf16x8*)&Pbuf[w][l15][quad * 8 + 32];
        lacc = __builtin_amdgcn_mfma_f32_16x16x32_bf16(pa0, ones, lacc, 0, 0, 0);
        lacc = __builtin_amdgcn_mfma_f32_16x16x32_bf16(pa1, ones, lacc, 0, 0, 0);
#pragma unroll
        for (int ds = 0; ds < 4; ++ds) {
            const u16* vp = vt + vtb + (size_t)(ds * 16 + l15) * S_ + j0 + quad * 8;
            bf16x8 bv0 = *(const bf16x8*)(vp);
            bf16x8 bv1 = *(const bf16x8*)(vp + 32);
            o[ds] = __builtin_amdgcn_mfma_f32_16x16x32_bf16(pa0, bv0, o[ds], 0, 0, 0);
            o[ds] = __builtin_amdgcn_mfma_f32_16x16x32_bf16(pa1, bv1, o[ds], 0, 0, 0);
        }
    }

    // ---- epilogue ----
#pragma unroll
    for (int ds = 0; ds < 4; ++ds)
#pragma unroll
        for (int reg = 0; reg < 4; ++reg) {
            int i = wi0 + quad * 4 + reg;
            out[((size_t)b * S_ + i) * H_ + n * DH + ds * 16 + l15] =
                o[ds][reg] / lacc[reg];
        }
}

// ---------------------------------------------------------------------------
extern "C" void kernel_launch(void* const* d_in, const int* in_sizes, int n_in,
                              void* d_out, int out_size, void* d_ws, size_t ws_size,
                              hipStream_t stream)
{
    const float* hs   = (const float*)d_in[0];
    const float* mask = (const float*)d_in[1];
    const float* adj  = (const float*)d_in[2];
    const float* Wq   = (const float*)d_in[3];
    const float* bq   = (const float*)d_in[4];
    const float* Wk   = (const float*)d_in[5];
    const float* bk   = (const float*)d_in[6];
    const float* Wv   = (const float*)d_in[7];
    const float* bv   = (const float*)d_in[8];
    const float* bili = (const float*)d_in[9];
    const float* absb = (const float*)d_in[10];
    float* out = (float*)d_out;

    u16* q  = (u16*)d_ws;
    u16* k  = q  + (size_t)BN * S_ * DH;
    u16* v  = k  + (size_t)BN * S_ * DH;
    u16* vt = v  + (size_t)BN * S_ * DH;
    unsigned char* adjp = (unsigned char*)(vt + (size_t)BN * S_ * DH);

    qkv_gemm<<<dim3(36, 64), 256, 0, stream>>>(hs, Wq, bq, Wk, bk, Wv, bv, q, k, v);
    vtrans<<<dim3(BN, 32), 256, 0, stream>>>(v, vt);
    adjpack<<<8192, 256, 0, stream>>>(adj, adjp);
    attn<<<dim3(BN, 32), 256, 0, stream>>>(q, k, vt, bili, adjp, mask, absb, out);
}

// Round 4
// 673.599 us; speedup vs baseline: 2.9977x; 1.0098x over previous
//
#include <hip/hip_runtime.h>
#include <cstdint>
#include <cstddef>

#define B_  2
#define S_  2048
#define H_  768
#define NH  12
#define DH  64
#define RD  5
#define BN  (B_*NH)   // 24

typedef _Float16 f16;
typedef __attribute__((ext_vector_type(8))) _Float16 f16x8;
typedef __attribute__((ext_vector_type(4))) float f32x4;

#define MFMA16(a, b, c) __builtin_amdgcn_mfma_f32_16x16x32_f16((a), (b), (c), 0, 0, 0)

#if __has_builtin(__builtin_amdgcn_exp2f)
__device__ __forceinline__ float exp2fast(float x) { return __builtin_amdgcn_exp2f(x); }
#else
__device__ __forceinline__ float exp2fast(float x) { return __expf(0.69314718056f * x); }
#endif

#define SCL 0.1803368801f   /* 0.125 * log2(e) */
#define L2E 1.44269504f

__device__ __forceinline__ void cvt16(const float* __restrict__ src, f16* dst) {
    float4 f0 = ((const float4*)src)[0];
    float4 f1 = ((const float4*)src)[1];
    float4 f2 = ((const float4*)src)[2];
    float4 f3 = ((const float4*)src)[3];
    f16x8 h0, h1;
    h0[0] = (f16)f0.x; h0[1] = (f16)f0.y; h0[2] = (f16)f0.z; h0[3] = (f16)f0.w;
    h0[4] = (f16)f1.x; h0[5] = (f16)f1.y; h0[6] = (f16)f1.z; h0[7] = (f16)f1.w;
    h1[0] = (f16)f2.x; h1[1] = (f16)f2.y; h1[2] = (f16)f2.z; h1[3] = (f16)f2.w;
    h1[4] = (f16)f3.x; h1[5] = (f16)f3.y; h1[6] = (f16)f3.z; h1[7] = (f16)f3.w;
    *(f16x8*)dst = h0;
    *(f16x8*)(dst + 8) = h1;
}

// ---------------------------------------------------------------------------
// Kernel 1: MFMA QKV projection.  One block: 64 rows x 64 cols of q,k,v
// (same x tile, three W tiles).  V written transposed (vt[bn][d][s]).
// grid (12, 64).
// ---------------------------------------------------------------------------
__global__ __launch_bounds__(256, 3) void qkv_gemm(
    const float* __restrict__ x,
    const float* __restrict__ Wq, const float* __restrict__ bq,
    const float* __restrict__ Wk, const float* __restrict__ bk,
    const float* __restrict__ Wv, const float* __restrict__ bv,
    f16* __restrict__ qo, f16* __restrict__ ko, f16* __restrict__ vt)
{
    __shared__ __align__(16) f16 Xs[64][72];
    __shared__ __align__(16) f16 Ws[3][64][72];

    const int tid = threadIdx.x;
    const int n  = blockIdx.x;          // head / 64-col tile
    const int m0 = blockIdx.y * 64;
    const int w = tid >> 6, lane = tid & 63;
    const int l15 = lane & 15, quad = lane >> 4;
    const int srow = tid >> 2, sc0 = (tid & 3) * 16;

    f32x4 acc[3][4];
#pragma unroll
    for (int i = 0; i < 3; ++i)
#pragma unroll
        for (int ns = 0; ns < 4; ++ns) acc[i][ns] = (f32x4){0.f, 0.f, 0.f, 0.f};

    const float* xsrc = x + (size_t)(m0 + srow) * H_ + sc0;
    const float* wsrc[3];
    wsrc[0] = Wq + (size_t)(n * 64 + srow) * H_ + sc0;
    wsrc[1] = Wk + (size_t)(n * 64 + srow) * H_ + sc0;
    wsrc[2] = Wv + (size_t)(n * 64 + srow) * H_ + sc0;

    for (int kc = 0; kc < 12; ++kc) {
        __syncthreads();
        cvt16(xsrc + kc * 64, &Xs[srow][sc0]);
#pragma unroll
        for (int i = 0; i < 3; ++i)
            cvt16(wsrc[i] + kc * 64, &Ws[i][srow][sc0]);
        __syncthreads();

        f16x8 a0 = *(const f16x8*)&Xs[w * 16 + l15][quad * 8];
        f16x8 a1 = *(const f16x8*)&Xs[w * 16 + l15][quad * 8 + 32];
#pragma unroll
        for (int i = 0; i < 3; ++i)
#pragma unroll
            for (int ns = 0; ns < 4; ++ns) {
                f16x8 b0 = *(const f16x8*)&Ws[i][ns * 16 + l15][quad * 8];
                f16x8 b1 = *(const f16x8*)&Ws[i][ns * 16 + l15][quad * 8 + 32];
                acc[i][ns] = MFMA16(a0, b0, acc[i][ns]);
                acc[i][ns] = MFMA16(a1, b1, acc[i][ns]);
            }
    }
    __syncthreads();

    // bias + write C tiles (transposed layout) into LDS
    const float* bias[3] = {bq, bk, bv};
    f16 (*T0)[72] = Xs;      // q
    f16 (*T1)[72] = Ws[0];   // k
    f16 (*T2)[72] = Ws[1];   // v
#pragma unroll
    for (int i = 0; i < 3; ++i) {
        f16 (*T)[72] = (i == 0) ? T0 : (i == 1) ? T1 : T2;
#pragma unroll
        for (int ns = 0; ns < 4; ++ns) {
            float bb = bias[i][n * 64 + ns * 16 + l15];
#pragma unroll
            for (int reg = 0; reg < 4; ++reg)
                T[w * 16 + quad * 4 + reg][ns * 16 + l15] =
                    (f16)(acc[i][ns][reg] + bb);
        }
    }
    __syncthreads();

    const int mrow = m0 + srow;
    const int bb2 = mrow >> 11, ss = mrow & 2047;
    {
        f16* dst = qo + ((size_t)(bb2 * NH + n) * S_ + ss) * DH + sc0;
        *(f16x8*)dst       = *(const f16x8*)&T0[srow][sc0];
        *(f16x8*)(dst + 8) = *(const f16x8*)&T0[srow][sc0 + 8];
    }
    {
        f16* dst = ko + ((size_t)(bb2 * NH + n) * S_ + ss) * DH + sc0;
        *(f16x8*)dst       = *(const f16x8*)&T1[srow][sc0];
        *(f16x8*)(dst + 8) = *(const f16x8*)&T1[srow][sc0 + 8];
    }
    {
        // transpose store for V: this thread handles row d=srow, s-chunk sc0
        f16 tmp[16];
#pragma unroll
        for (int u = 0; u < 16; ++u) tmp[u] = T2[sc0 + u][srow];
        f16* dst = vt + ((size_t)(bb2 * NH + n) * DH + srow) * S_ + (m0 & 2047) + sc0;
        *(f16x8*)dst       = *(const f16x8*)&tmp[0];
        *(f16x8*)(dst + 8) = *(const f16x8*)&tmp[8];
    }
}

// ---------------------------------------------------------------------------
// Kernel 2: pack binary adjacency -> bytes, i-quad interleaved.
// ---------------------------------------------------------------------------
__global__ __launch_bounds__(256) void adjpack(
    const float* __restrict__ adj, unsigned char* __restrict__ adjp)
{
    const int idx = blockIdx.x * 256 + threadIdx.x;   // [0, 2^21)
    const int j  = idx & 2047;
    const int iq = (idx >> 11) & 511;
    const int b  = idx >> 20;
    unsigned int bits[4] = {0, 0, 0, 0};
#pragma unroll
    for (int r = 0; r < RD; ++r) {
#pragma unroll
        for (int ii = 0; ii < 4; ++ii) {
            float a = adj[(((size_t)(r * B_ + b) * S_) + iq * 4 + ii) * S_ + j];
            bits[ii] |= (a != 0.f ? 1u : 0u) << r;
        }
    }
    uchar4 pk;
    pk.x = (unsigned char)bits[0];
    pk.y = (unsigned char)bits[1];
    pk.z = (unsigned char)bits[2];
    pk.w = (unsigned char)bits[3];
    *(uchar4*)(adjp + (size_t)idx * 4) = pk;
}

// ---------------------------------------------------------------------------
// Kernel 3: MFMA flash attention, j-split across wave pairs.
// Block = (bn, 32-row i-tile); waves 0,1: rows, j in [0,1024);
// waves 2,3: same rows, j in [1024,2048). Merge states in LDS at end.
// ---------------------------------------------------------------------------
__global__ __launch_bounds__(256, 4) void attn(
    const f16* __restrict__ q, const f16* __restrict__ k, const f16* __restrict__ vt,
    const float* __restrict__ bili, const unsigned char* __restrict__ adjp,
    const float* __restrict__ mask, const float* __restrict__ absb,
    float* __restrict__ out)
{
    __shared__ __align__(16) char smem[12800 + 9216 + 128];
    f16*   Mt  = (f16*)smem;                     // [64][72]  (prologue only)
    float* Mg  = (float*)smem;                   // [2][64][25] (merge, reuses Mt)
    f16*   Pb  = (f16*)(smem + 12800);           // [4][16][72]
    float* lut = (float*)(smem + 12800 + 9216);  // [32]

    const int tid = threadIdx.x;
    const int bn = blockIdx.x, it = blockIdx.y;
    const int b = bn / NH, n = bn % NH;
    const int w = tid >> 6, lane = tid & 63;
    const int l15 = lane & 15, quad = lane >> 4;
    const int wrow = w & 1, half = w >> 1;
    const int wi0 = it * 32 + wrow * 16;
    const size_t kbase = (size_t)bn * S_ * DH;

    if (tid < 32) {
        float a = 0.f;
#pragma unroll
        for (int r = 0; r < RD; ++r)
            if (tid & (1 << r)) a += absb[r * NH + n];
        lut[tid] = a * SCL;
    }

    const f16* qrow = q + kbase + (size_t)(wi0 + l15) * DH + quad * 8;
    f16x8 aq0 = *(const f16x8*)(qrow);
    f16x8 aq1 = *(const f16x8*)(qrow + 32);

    f16* Pw = Pb + w * 16 * 72;

    // ---- build Q'_r A-frags via MFMA ----
    f16x8 aqp[RD][2];
#pragma unroll 1
    for (int r = 0; r < RD; ++r) {
        __syncthreads();
        {
            int p = tid >> 2, q0 = (tid & 3) * 16;
            const float* src = bili + ((size_t)(r * NH + n) * DH + p) * DH + q0;
            float4 g0 = ((const float4*)src)[0];
            float4 g1 = ((const float4*)src)[1];
            float4 g2 = ((const float4*)src)[2];
            float4 g3 = ((const float4*)src)[3];
            float mv[16] = {g0.x, g0.y, g0.z, g0.w, g1.x, g1.y, g1.z, g1.w,
                            g2.x, g2.y, g2.z, g2.w, g3.x, g3.y, g3.z, g3.w};
#pragma unroll
            for (int u = 0; u < 16; ++u) Mt[(q0 + u) * 72 + p] = (f16)mv[u];
        }
        __syncthreads();
#pragma unroll
        for (int ns = 0; ns < 4; ++ns) {
            f16x8 b0 = *(const f16x8*)&Mt[(ns * 16 + l15) * 72 + quad * 8];
            f16x8 b1 = *(const f16x8*)&Mt[(ns * 16 + l15) * 72 + quad * 8 + 32];
            f32x4 d = {0.f, 0.f, 0.f, 0.f};
            d = MFMA16(aq0, b0, d);
            d = MFMA16(aq1, b1, d);
#pragma unroll
            for (int reg = 0; reg < 4; ++reg)
                Pw[(quad * 4 + reg) * 72 + ns * 16 + l15] = (f16)d[reg];
        }
        aqp[r][0] = *(const f16x8*)&Pw[l15 * 72 + quad * 8];
        aqp[r][1] = *(const f16x8*)&Pw[l15 * 72 + quad * 8 + 32];
    }
    __syncthreads();   // Mt dead; Mg may be written later

    f16x8 ones;
#pragma unroll
    for (int u = 0; u < 8; ++u) ones[u] = (f16)1.0f;

    f32x4 o[4] = {{0,0,0,0},{0,0,0,0},{0,0,0,0},{0,0,0,0}};
    f32x4 lacc = {0.f, 0.f, 0.f, 0.f};
    float mrun[4] = {-1e30f, -1e30f, -1e30f, -1e30f};

    const unsigned char* adjrow =
        adjp + (size_t)(b * 512 + (wi0 >> 2) + quad) * (S_ * 4);
    const float* maskrow = mask + (size_t)b * S_;
    const f16* vtb = vt + (size_t)bn * DH * S_;

    for (int t = 0; t < 16; ++t) {
        const int j0 = half * 1024 + t * 64;
        float sc[4][4];

#pragma unroll
        for (int js = 0; js < 4; ++js) {
            const int jcol = j0 + js * 16 + l15;
            const f16* kp = k + kbase + (size_t)jcol * DH + quad * 8;
            f16x8 bk0 = *(const f16x8*)(kp);
            f16x8 bk1 = *(const f16x8*)(kp + 32);

            f32x4 aqk = {0.f, 0.f, 0.f, 0.f};
            aqk = MFMA16(aq0, bk0, aqk);
            aqk = MFMA16(aq1, bk1, aqk);
            f32x4 ar[RD];
#pragma unroll
            for (int r = 0; r < RD; ++r) {
                f32x4 z = {0.f, 0.f, 0.f, 0.f};
                z = MFMA16(aqp[r][0], bk0, z);
                z = MFMA16(aqp[r][1], bk1, z);
                ar[r] = z;
            }

            uchar4 a4 = *(const uchar4*)(adjrow + (size_t)jcol * 4);
            unsigned int bbits[4] = {a4.x, a4.y, a4.z, a4.w};
            float mkL = maskrow[jcol] * L2E;
#pragma unroll
            for (int reg = 0; reg < 4; ++reg) {
                float s = aqk[reg];
                unsigned int bt = bbits[reg];
#pragma unroll
                for (int r = 0; r < RD; ++r)
                    s = fmaf((float)((bt >> r) & 1u), ar[r][reg], s);
                sc[js][reg] = fmaf(s, SCL, lut[bt] + mkL);
            }
        }

        // ---- online softmax (exp2 domain; rows in 16-lane groups) ----
        float alpha[4];
#pragma unroll
        for (int reg = 0; reg < 4; ++reg) {
            float nm = fmaxf(fmaxf(sc[0][reg], sc[1][reg]),
                             fmaxf(sc[2][reg], sc[3][reg]));
#pragma unroll
            for (int off = 1; off < 16; off <<= 1)
                nm = fmaxf(nm, __shfl_xor(nm, off));
            float mn = fmaxf(mrun[reg], nm);
            alpha[reg] = exp2fast(mrun[reg] - mn);
            mrun[reg] = mn;
        }
#pragma unroll
        for (int js = 0; js < 4; ++js)
#pragma unroll
            for (int reg = 0; reg < 4; ++reg) {
                float p = exp2fast(sc[js][reg] - mrun[reg]);
                Pw[(quad * 4 + reg) * 72 + js * 16 + l15] = (f16)p;
            }
#pragma unroll
        for (int reg = 0; reg < 4; ++reg) {
            lacc[reg] *= alpha[reg];
#pragma unroll
            for (int ds = 0; ds < 4; ++ds) o[ds][reg] *= alpha[reg];
        }

        // ---- PV + row-sum via MFMA ----
        f16x8 pa0 = *(const f16x8*)&Pw[l15 * 72 + quad * 8];
        f16x8 pa1 = *(const f16x8*)&Pw[l15 * 72 + quad * 8 + 32];
        lacc = MFMA16(pa0, ones, lacc);
        lacc = MFMA16(pa1, ones, lacc);
#pragma unroll
        for (int ds = 0; ds < 4; ++ds) {
            const f16* vp = vtb + (size_t)(ds * 16 + l15) * S_ + j0 + quad * 8;
            f16x8 bv0 = *(const f16x8*)(vp);
            f16x8 bv1 = *(const f16x8*)(vp + 32);
            o[ds] = MFMA16(pa0, bv0, o[ds]);
            o[ds] = MFMA16(pa1, bv1, o[ds]);
        }
    }

    // ---- merge j-halves ----
    if (half == 1) {
        float* g = Mg + ((size_t)wrow * 64 + lane) * 25;
#pragma unroll
        for (int ds = 0; ds < 4; ++ds)
#pragma unroll
            for (int reg = 0; reg < 4; ++reg) g[ds * 4 + reg] = o[ds][reg];
#pragma unroll
        for (int reg = 0; reg < 4; ++reg) {
            g[16 + reg] = lacc[reg];
            g[20 + reg] = mrun[reg];
        }
    }
    __syncthreads();
    if (half == 0) {
        const float* g = Mg + ((size_t)wrow * 64 + lane) * 25;
#pragma unroll
        for (int reg = 0; reg < 4; ++reg) {
            float m1 = g[20 + reg];
            float mm = fmaxf(mrun[reg], m1);
            float fa = exp2fast(mrun[reg] - mm);
            float fb = exp2fast(m1 - mm);
            float l = lacc[reg] * fa + g[16 + reg] * fb;
            float inv = 1.f / l;
            int i = wi0 + quad * 4 + reg;
#pragma unroll
            for (int ds = 0; ds < 4; ++ds) {
                float ov = o[ds][reg] * fa + g[ds * 4 + reg] * fb;
                out[((size_t)b * S_ + i) * H_ + n * DH + ds * 16 + l15] = ov * inv;
            }
        }
    }
}

// ---------------------------------------------------------------------------
extern "C" void kernel_launch(void* const* d_in, const int* in_sizes, int n_in,
                              void* d_out, int out_size, void* d_ws, size_t ws_size,
                              hipStream_t stream)
{
    const float* hs   = (const float*)d_in[0];
    const float* mask = (const float*)d_in[1];
    const float* adj  = (const float*)d_in[2];
    const float* Wq   = (const float*)d_in[3];
    const float* bq   = (const float*)d_in[4];
    const float* Wk   = (const float*)d_in[5];
    const float* bk   = (const float*)d_in[6];
    const float* Wv   = (const float*)d_in[7];
    const float* bv   = (const float*)d_in[8];
    const float* bili = (const float*)d_in[9];
    const float* absb = (const float*)d_in[10];
    float* out = (float*)d_out;

    f16* q  = (f16*)d_ws;
    f16* k  = q + (size_t)BN * S_ * DH;
    f16* vt = k + (size_t)BN * S_ * DH;
    unsigned char* adjp = (unsigned char*)(vt + (size_t)BN * S_ * DH);

    qkv_gemm<<<dim3(12, 64), 256, 0, stream>>>(hs, Wq, bq, Wk, bk, Wv, bv, q, k, vt);
    adjpack<<<8192, 256, 0, stream>>>(adj, adjp);
    attn<<<dim3(BN, 64), 256, 0, stream>>>(q, k, vt, bili, adjp, mask, absb, out);
}

// Round 5
// 526.213 us; speedup vs baseline: 3.8373x; 1.2801x over previous
//
#include <hip/hip_runtime.h>
#include <cstdint>
#include <cstddef>

#define B_  2
#define S_  2048
#define H_  768
#define NH  12
#define DH  64
#define RD  5
#define BN  (B_*NH)   // 24

typedef _Float16 f16;
typedef __attribute__((ext_vector_type(8))) _Float16 f16x8;
typedef __attribute__((ext_vector_type(4))) float f32x4;

#define MFMA16(a, b, c) __builtin_amdgcn_mfma_f32_16x16x32_f16((a), (b), (c), 0, 0, 0)

#if __has_builtin(__builtin_amdgcn_exp2f)
__device__ __forceinline__ float exp2fast(float x) { return __builtin_amdgcn_exp2f(x); }
#else
__device__ __forceinline__ float exp2fast(float x) { return __expf(0.69314718056f * x); }
#endif

#define SCL 0.1803368801f   /* 0.125 * log2(e) */
#define L2E 1.44269504f

// ---------------------------------------------------------------------------
// Kernel 0: fp32 -> fp16 conversion (x and the three W matrices, once).
// ---------------------------------------------------------------------------
__global__ __launch_bounds__(256) void cvtf16(
    const float* __restrict__ src, f16* __restrict__ dst, int n4)
{
    int idx = blockIdx.x * 256 + threadIdx.x;
    if (idx >= n4) return;
    float4 f = ((const float4*)src)[idx];
    f16 h[4] = {(f16)f.x, (f16)f.y, (f16)f.z, (f16)f.w};
    ((ushort4*)dst)[idx] = *(const ushort4*)h;
}

// ---------------------------------------------------------------------------
// Kernel 1: MFMA QKV projection (fp16 in/out).  One block: 64 rows x 64 cols
// of q,k,v (same x tile, three W tiles).  V written transposed vt[bn][d][s].
// grid (12, 64).
// ---------------------------------------------------------------------------
__global__ __launch_bounds__(256, 3) void qkv_gemm(
    const f16* __restrict__ xh, const f16* __restrict__ wh,
    const float* __restrict__ bq, const float* __restrict__ bk,
    const float* __restrict__ bv,
    f16* __restrict__ qo, f16* __restrict__ ko, f16* __restrict__ vt)
{
    __shared__ __align__(16) f16 Xs[64][72];
    __shared__ __align__(16) f16 Ws[3][64][72];

    const int tid = threadIdx.x;
    const int n  = blockIdx.x;          // head / 64-col tile
    const int m0 = blockIdx.y * 64;
    const int w = tid >> 6, lane = tid & 63;
    const int l15 = lane & 15, quad = lane >> 4;
    const int srow = tid >> 2, sc0 = (tid & 3) * 16;

    f32x4 acc[3][4];
#pragma unroll
    for (int i = 0; i < 3; ++i)
#pragma unroll
        for (int ns = 0; ns < 4; ++ns) acc[i][ns] = (f32x4){0.f, 0.f, 0.f, 0.f};

    const f16* xsrc = xh + (size_t)(m0 + srow) * H_ + sc0;
    const f16* wsrc = wh + (size_t)(n * 64 + srow) * H_ + sc0;   // Wq slice

    for (int kc = 0; kc < 12; ++kc) {
        __syncthreads();
        {
            const f16* s0 = xsrc + kc * 64;
            *(f16x8*)&Xs[srow][sc0]     = *(const f16x8*)(s0);
            *(f16x8*)&Xs[srow][sc0 + 8] = *(const f16x8*)(s0 + 8);
        }
#pragma unroll
        for (int i = 0; i < 3; ++i) {
            const f16* s0 = wsrc + (size_t)i * H_ * H_ + kc * 64;
            *(f16x8*)&Ws[i][srow][sc0]     = *(const f16x8*)(s0);
            *(f16x8*)&Ws[i][srow][sc0 + 8] = *(const f16x8*)(s0 + 8);
        }
        __syncthreads();

        f16x8 a0 = *(const f16x8*)&Xs[w * 16 + l15][quad * 8];
        f16x8 a1 = *(const f16x8*)&Xs[w * 16 + l15][quad * 8 + 32];
#pragma unroll
        for (int i = 0; i < 3; ++i)
#pragma unroll
            for (int ns = 0; ns < 4; ++ns) {
                f16x8 b0 = *(const f16x8*)&Ws[i][ns * 16 + l15][quad * 8];
                f16x8 b1 = *(const f16x8*)&Ws[i][ns * 16 + l15][quad * 8 + 32];
                acc[i][ns] = MFMA16(a0, b0, acc[i][ns]);
                acc[i][ns] = MFMA16(a1, b1, acc[i][ns]);
            }
    }
    __syncthreads();

    // bias + write C tiles (transposed layout) into LDS
    const float* bias[3] = {bq, bk, bv};
    f16 (*T0)[72] = Xs;      // q
    f16 (*T1)[72] = Ws[0];   // k
    f16 (*T2)[72] = Ws[1];   // v
#pragma unroll
    for (int i = 0; i < 3; ++i) {
        f16 (*T)[72] = (i == 0) ? T0 : (i == 1) ? T1 : T2;
#pragma unroll
        for (int ns = 0; ns < 4; ++ns) {
            float bb = bias[i][n * 64 + ns * 16 + l15];
#pragma unroll
            for (int reg = 0; reg < 4; ++reg)
                T[w * 16 + quad * 4 + reg][ns * 16 + l15] =
                    (f16)(acc[i][ns][reg] + bb);
        }
    }
    __syncthreads();

    const int mrow = m0 + srow;
    const int bb2 = mrow >> 11, ss = mrow & 2047;
    {
        f16* dst = qo + ((size_t)(bb2 * NH + n) * S_ + ss) * DH + sc0;
        *(f16x8*)dst       = *(const f16x8*)&T0[srow][sc0];
        *(f16x8*)(dst + 8) = *(const f16x8*)&T0[srow][sc0 + 8];
    }
    {
        f16* dst = ko + ((size_t)(bb2 * NH + n) * S_ + ss) * DH + sc0;
        *(f16x8*)dst       = *(const f16x8*)&T1[srow][sc0];
        *(f16x8*)(dst + 8) = *(const f16x8*)&T1[srow][sc0 + 8];
    }
    {
        // transpose store for V: row d=srow, s-chunk sc0
        f16 tmp[16];
#pragma unroll
        for (int u = 0; u < 16; ++u) tmp[u] = T2[sc0 + u][srow];
        f16* dst = vt + ((size_t)(bb2 * NH + n) * DH + srow) * S_ + (m0 & 2047) + sc0;
        *(f16x8*)dst       = *(const f16x8*)&tmp[0];
        *(f16x8*)(dst + 8) = *(const f16x8*)&tmp[8];
    }
}

// ---------------------------------------------------------------------------
// Kernel 2: pack binary adjacency -> bytes, i-quad interleaved.
// ---------------------------------------------------------------------------
__global__ __launch_bounds__(256) void adjpack(
    const float* __restrict__ adj, unsigned char* __restrict__ adjp)
{
    const int idx = blockIdx.x * 256 + threadIdx.x;   // [0, 2^21)
    const int j  = idx & 2047;
    const int iq = (idx >> 11) & 511;
    const int b  = idx >> 20;
    unsigned int bits[4] = {0, 0, 0, 0};
#pragma unroll
    for (int r = 0; r < RD; ++r) {
#pragma unroll
        for (int ii = 0; ii < 4; ++ii) {
            float a = adj[(((size_t)(r * B_ + b) * S_) + iq * 4 + ii) * S_ + j];
            bits[ii] |= (a != 0.f ? 1u : 0u) << r;
        }
    }
    uchar4 pk;
    pk.x = (unsigned char)bits[0];
    pk.y = (unsigned char)bits[1];
    pk.z = (unsigned char)bits[2];
    pk.w = (unsigned char)bits[3];
    *(uchar4*)(adjp + (size_t)idx * 4) = pk;
}

// ---------------------------------------------------------------------------
// Kernel 3: MFMA flash attention.  Block = (bn, 64-row i-tile), 4 waves,
// each wave owns 16 rows and the FULL j range.  No barriers in j-loop.
// launch_bounds(256,3): measured spill-free (VGPR 72); (256,4) spilled.
// ---------------------------------------------------------------------------
__global__ __launch_bounds__(256, 3) void attn(
    const f16* __restrict__ q, const f16* __restrict__ k, const f16* __restrict__ vt,
    const float* __restrict__ bili, const unsigned char* __restrict__ adjp,
    const float* __restrict__ mask, const float* __restrict__ absb,
    float* __restrict__ out)
{
    __shared__ __align__(16) char smem[9216 + 9216 + 128];
    f16*   Mt  = (f16*)smem;                    // [64][72] (prologue only)
    f16*   Pb  = (f16*)(smem + 9216);           // [4][16][72]
    float* lut = (float*)(smem + 9216 + 9216);  // [32]

    const int tid = threadIdx.x;
    const int bn = blockIdx.x, it = blockIdx.y;
    const int b = bn / NH, n = bn % NH;
    const int w = tid >> 6, lane = tid & 63;
    const int l15 = lane & 15, quad = lane >> 4;
    const int wi0 = it * 64 + w * 16;
    const size_t kbase = (size_t)bn * S_ * DH;

    if (tid < 32) {
        float a = 0.f;
#pragma unroll
        for (int r = 0; r < RD; ++r)
            if (tid & (1 << r)) a += absb[r * NH + n];
        lut[tid] = a * SCL;
    }

    const f16* qrow = q + kbase + (size_t)(wi0 + l15) * DH + quad * 8;
    f16x8 aq0 = *(const f16x8*)(qrow);
    f16x8 aq1 = *(const f16x8*)(qrow + 32);

    f16* Pw = Pb + w * 16 * 72;

    // ---- build Q'_r A-frags via MFMA (M_r staged transposed in LDS) ----
    f16x8 aqp[RD][2];
#pragma unroll 1
    for (int r = 0; r < RD; ++r) {
        __syncthreads();
        {
            int p = tid >> 2, q0 = (tid & 3) * 16;
            const float* src = bili + ((size_t)(r * NH + n) * DH + p) * DH + q0;
            float4 g0 = ((const float4*)src)[0];
            float4 g1 = ((const float4*)src)[1];
            float4 g2 = ((const float4*)src)[2];
            float4 g3 = ((const float4*)src)[3];
            float mv[16] = {g0.x, g0.y, g0.z, g0.w, g1.x, g1.y, g1.z, g1.w,
                            g2.x, g2.y, g2.z, g2.w, g3.x, g3.y, g3.z, g3.w};
#pragma unroll
            for (int u = 0; u < 16; ++u) Mt[(q0 + u) * 72 + p] = (f16)mv[u];
        }
        __syncthreads();
#pragma unroll
        for (int ns = 0; ns < 4; ++ns) {
            f16x8 b0 = *(const f16x8*)&Mt[(ns * 16 + l15) * 72 + quad * 8];
            f16x8 b1 = *(const f16x8*)&Mt[(ns * 16 + l15) * 72 + quad * 8 + 32];
            f32x4 d = {0.f, 0.f, 0.f, 0.f};
            d = MFMA16(aq0, b0, d);
            d = MFMA16(aq1, b1, d);
#pragma unroll
            for (int reg = 0; reg < 4; ++reg)
                Pw[(quad * 4 + reg) * 72 + ns * 16 + l15] = (f16)d[reg];
        }
        aqp[r][0] = *(const f16x8*)&Pw[l15 * 72 + quad * 8];
        aqp[r][1] = *(const f16x8*)&Pw[l15 * 72 + quad * 8 + 32];
    }

    f16x8 ones;
#pragma unroll
    for (int u = 0; u < 8; ++u) ones[u] = (f16)1.0f;

    f32x4 o[4] = {{0,0,0,0},{0,0,0,0},{0,0,0,0},{0,0,0,0}};
    f32x4 lacc = {0.f, 0.f, 0.f, 0.f};
    float mrun[4] = {-1e30f, -1e30f, -1e30f, -1e30f};

    const unsigned char* adjrow =
        adjp + (size_t)(b * 512 + (wi0 >> 2) + quad) * (S_ * 4);
    const float* maskrow = mask + (size_t)b * S_;
    const f16* vtb = vt + (size_t)bn * DH * S_;

    for (int t = 0; t < 32; ++t) {
        const int j0 = t * 64;
        float sc[4][4];

#pragma unroll
        for (int js = 0; js < 4; ++js) {
            const int jcol = j0 + js * 16 + l15;
            const f16* kp = k + kbase + (size_t)jcol * DH + quad * 8;
            f16x8 bk0 = *(const f16x8*)(kp);
            f16x8 bk1 = *(const f16x8*)(kp + 32);

            f32x4 aqk = {0.f, 0.f, 0.f, 0.f};
            aqk = MFMA16(aq0, bk0, aqk);
            aqk = MFMA16(aq1, bk1, aqk);
            f32x4 ar[RD];
#pragma unroll
            for (int r = 0; r < RD; ++r) {
                f32x4 z = {0.f, 0.f, 0.f, 0.f};
                z = MFMA16(aqp[r][0], bk0, z);
                z = MFMA16(aqp[r][1], bk1, z);
                ar[r] = z;
            }

            uchar4 a4 = *(const uchar4*)(adjrow + (size_t)jcol * 4);
            unsigned int bbits[4] = {a4.x, a4.y, a4.z, a4.w};
            float mkL = maskrow[jcol] * L2E;
#pragma unroll
            for (int reg = 0; reg < 4; ++reg) {
                float s = aqk[reg];
                unsigned int bt = bbits[reg];
#pragma unroll
                for (int r = 0; r < RD; ++r)
                    s = fmaf((float)((bt >> r) & 1u), ar[r][reg], s);
                sc[js][reg] = fmaf(s, SCL, lut[bt] + mkL);
            }
        }

        // ---- online softmax (exp2 domain; rows in 16-lane groups) ----
        float alpha[4];
#pragma unroll
        for (int reg = 0; reg < 4; ++reg) {
            float nm = fmaxf(fmaxf(sc[0][reg], sc[1][reg]),
                             fmaxf(sc[2][reg], sc[3][reg]));
#pragma unroll
            for (int off = 1; off < 16; off <<= 1)
                nm = fmaxf(nm, __shfl_xor(nm, off));
            float mn = fmaxf(mrun[reg], nm);
            alpha[reg] = exp2fast(mrun[reg] - mn);
            mrun[reg] = mn;
        }
#pragma unroll
        for (int js = 0; js < 4; ++js)
#pragma unroll
            for (int reg = 0; reg < 4; ++reg) {
                float p = exp2fast(sc[js][reg] - mrun[reg]);
                Pw[(quad * 4 + reg) * 72 + js * 16 + l15] = (f16)p;
            }
#pragma unroll
        for (int reg = 0; reg < 4; ++reg) {
            lacc[reg] *= alpha[reg];
#pragma unroll
            for (int ds = 0; ds < 4; ++ds) o[ds][reg] *= alpha[reg];
        }

        // ---- PV + row-sum via MFMA ----
        f16x8 pa0 = *(const f16x8*)&Pw[l15 * 72 + quad * 8];
        f16x8 pa1 = *(const f16x8*)&Pw[l15 * 72 + quad * 8 + 32];
        lacc = MFMA16(pa0, ones, lacc);
        lacc = MFMA16(pa1, ones, lacc);
#pragma unroll
        for (int ds = 0; ds < 4; ++ds) {
            const f16* vp = vtb + (size_t)(ds * 16 + l15) * S_ + j0 + quad * 8;
            f16x8 bv0 = *(const f16x8*)(vp);
            f16x8 bv1 = *(const f16x8*)(vp + 32);
            o[ds] = MFMA16(pa0, bv0, o[ds]);
            o[ds] = MFMA16(pa1, bv1, o[ds]);
        }
    }

    // ---- epilogue ----
#pragma unroll
    for (int reg = 0; reg < 4; ++reg) {
        float inv = 1.f / lacc[reg];
        int i = wi0 + quad * 4 + reg;
#pragma unroll
        for (int ds = 0; ds < 4; ++ds)
            out[((size_t)b * S_ + i) * H_ + n * DH + ds * 16 + l15] =
                o[ds][reg] * inv;
    }
}

// ---------------------------------------------------------------------------
extern "C" void kernel_launch(void* const* d_in, const int* in_sizes, int n_in,
                              void* d_out, int out_size, void* d_ws, size_t ws_size,
                              hipStream_t stream)
{
    const float* hs   = (const float*)d_in[0];
    const float* mask = (const float*)d_in[1];
    const float* adj  = (const float*)d_in[2];
    const float* Wq   = (const float*)d_in[3];
    const float* bq   = (const float*)d_in[4];
    const float* Wk   = (const float*)d_in[5];
    const float* bk   = (const float*)d_in[6];
    const float* Wv   = (const float*)d_in[7];
    const float* bv   = (const float*)d_in[8];
    const float* bili = (const float*)d_in[9];
    const float* absb = (const float*)d_in[10];
    float* out = (float*)d_out;

    const size_t QKV = (size_t)BN * S_ * DH;       // 3.1M elems
    f16* q  = (f16*)d_ws;
    f16* k  = q + QKV;
    f16* vt = k + QKV;
    unsigned char* adjp = (unsigned char*)(vt + QKV);       // 8 MB
    f16* xh = (f16*)(adjp + (size_t)B_ * 512 * S_ * 4);
    f16* wh = xh + (size_t)B_ * S_ * H_;                    // Wq|Wk|Wv f16

    const int nx4 = (B_ * S_ * H_) / 4;
    const int nw4 = (H_ * H_) / 4;
    cvtf16<<<(nx4 + 255) / 256, 256, 0, stream>>>(hs, xh, nx4);
    cvtf16<<<(nw4 + 255) / 256, 256, 0, stream>>>(Wq, wh, nw4);
    cvtf16<<<(nw4 + 255) / 256, 256, 0, stream>>>(Wk, wh + (size_t)H_ * H_, nw4);
    cvtf16<<<(nw4 + 255) / 256, 256, 0, stream>>>(Wv, wh + (size_t)2 * H_ * H_, nw4);

    qkv_gemm<<<dim3(12, 64), 256, 0, stream>>>(xh, wh, bq, bk, bv, q, k, vt);
    adjpack<<<8192, 256, 0, stream>>>(adj, adjp);
    attn<<<dim3(BN, 32), 256, 0, stream>>>(q, k, vt, bili, adjp, mask, absb, out);
}